// Round 1
// baseline (211.203 us; speedup 1.0000x reference)
//
#include <hip/hip_runtime.h>

#define Nn 1024
#define Ee 65536
#define Pq 1024
#define Din 128
#define Hh 64

// ---------------- degree / norm ----------------
__global__ void k_deg(const int* __restrict__ ei, float* __restrict__ deg) {
    int e = blockIdx.x * blockDim.x + threadIdx.x;
    if (e < Ee) atomicAdd(&deg[ei[Ee + e]], 1.0f);
}

__global__ void k_dinv(const float* __restrict__ deg, float* __restrict__ dinv) {
    int i = blockIdx.x * blockDim.x + threadIdx.x;
    if (i < Nn) dinv[i] = rsqrtf(deg[i] + 1.0f);
}

// ---------------- xw = X @ W  (X:[Nn,K], W:[K,64]) ----------------
template <int K>
__global__ void k_xw(const float* __restrict__ X, const float* __restrict__ W,
                     float* __restrict__ xw) {
    int gid = blockIdx.x * blockDim.x + threadIdx.x;  // Nn*64 threads
    int r = gid >> 6, c = gid & 63;
    float acc = 0.f;
    #pragma unroll 8
    for (int j = 0; j < K; ++j) acc += X[r * K + j] * W[j * 64 + c];
    xw[gid] = acc;
}

// ---------------- GCN scatter: out[col] += xw[row]*dinv[row]*dinv[col] ----------------
__global__ void k_scatter(const int* __restrict__ ei, const float* __restrict__ xw,
                          const float* __restrict__ dinv, float* __restrict__ out) {
    int gid = blockIdx.x * blockDim.x + threadIdx.x;  // Ee*64 threads
    int e = gid >> 6, c = gid & 63;
    int r = ei[e], cl = ei[Ee + e];
    atomicAdd(&out[cl * 64 + c], xw[r * 64 + c] * dinv[r] * dinv[cl]);
}

// ---------------- self-loop message + bias ----------------
__global__ void k_selfloop(float* __restrict__ out, const float* __restrict__ xw,
                           const float* __restrict__ dinv, const float* __restrict__ b) {
    int gid = blockIdx.x * blockDim.x + threadIdx.x;  // Nn*64
    int n = gid >> 6, c = gid & 63;
    float di = dinv[n];
    out[gid] += xw[gid] * di * di + b[c];
}

// ---------------- edge-index maps (last-edge-wins == max id; dup edges have equal values) ----------------
__global__ void k_buildM(const int* __restrict__ ei, int* __restrict__ M, int* __restrict__ MT) {
    int e = blockIdx.x * blockDim.x + threadIdx.x;
    if (e < Ee) {
        int r = ei[e], cl = ei[Ee + e];
        atomicMax(&M[r * Nn + cl], e);
        atomicMax(&MT[cl * Nn + r], e);
    }
}

// ---------------- per-edge MLP heads: x1 = relu(LN(xe@W1+b1)), x2 = relu(LN(xe@W2+b2)) ----------------
__global__ __launch_bounds__(256) void k_mlp_edges(
    const int* __restrict__ ei, const float* __restrict__ h2,
    const float* __restrict__ W1, const float* __restrict__ b1,
    const float* __restrict__ g1, const float* __restrict__ be1,
    const float* __restrict__ W2, const float* __restrict__ b2,
    const float* __restrict__ g2, const float* __restrict__ be2,
    float* __restrict__ x1buf, float* __restrict__ x2buf) {
    __shared__ float W1s[64 * 64], W2s[64 * 64];
    __shared__ float vec[6 * 64];
    int tid = threadIdx.x;
    for (int i = tid; i < 4096; i += 256) { W1s[i] = W1[i]; W2s[i] = W2[i]; }
    if (tid < 64) {
        vec[tid] = b1[tid];        vec[64 + tid] = g1[tid];  vec[128 + tid] = be1[tid];
        vec[192 + tid] = b2[tid];  vec[256 + tid] = g2[tid]; vec[320 + tid] = be2[tid];
    }
    __syncthreads();
    int lane = tid & 63;
    int wgid = blockIdx.x * 4 + (tid >> 6);
    int nw = gridDim.x * 4;
    float lb1 = vec[lane], lg1 = vec[64 + lane], lbe1 = vec[128 + lane];
    float lb2 = vec[192 + lane], lg2 = vec[256 + lane], lbe2 = vec[320 + lane];
    for (int e = wgid; e < Ee; e += nw) {
        int r = ei[e], cl = ei[Ee + e];
        float xv = h2[r * 64 + lane] * h2[cl * 64 + lane];
        float a1 = lb1, a2 = lb2;
        #pragma unroll 8
        for (int j = 0; j < 64; ++j) {
            float v = __shfl(xv, j);
            a1 += v * W1s[j * 64 + lane];
            a2 += v * W2s[j * 64 + lane];
        }
        float s1 = a1, q1 = a1 * a1, s2 = a2, q2 = a2 * a2;
        for (int off = 32; off; off >>= 1) {
            s1 += __shfl_xor(s1, off); q1 += __shfl_xor(q1, off);
            s2 += __shfl_xor(s2, off); q2 += __shfl_xor(q2, off);
        }
        float mu1 = s1 * (1.f / 64.f), mu2 = s2 * (1.f / 64.f);
        float v1 = q1 * (1.f / 64.f) - mu1 * mu1;
        float v2 = q2 * (1.f / 64.f) - mu2 * mu2;
        float r1 = rsqrtf(v1 + 1e-5f), r2 = rsqrtf(v2 + 1e-5f);
        x1buf[e * 64 + lane] = fmaxf(0.f, (a1 - mu1) * r1 * lg1 + lbe1);
        x2buf[e * 64 + lane] = fmaxf(0.f, (a2 - mu2) * r2 * lg2 + lbe2);
    }
}

// ---------------- xx pairs -> feat[:,64:128] ----------------
__global__ void k_xx(const int* __restrict__ pos, const float* __restrict__ h2,
                     float* __restrict__ feat) {
    int gid = blockIdx.x * blockDim.x + threadIdx.x;  // Pq*64
    int p = gid >> 6, c = gid & 63;
    feat[p * 128 + 64 + c] = h2[pos[p] * 64 + c] * h2[pos[Pq + p] * 64 + c];
}

// ---------------- pos_val[p,h] = sum_k x2[M[a,k]] * x1[MT[b,k]] -> feat[:,0:64] ----------------
__global__ __launch_bounds__(64) void k_posval(const int* __restrict__ pos,
                                               const int* __restrict__ M,
                                               const int* __restrict__ MT,
                                               const float* __restrict__ x1buf,
                                               const float* __restrict__ x2buf,
                                               float* __restrict__ feat) {
    int p = blockIdx.x;
    int lane = threadIdx.x;
    int a = pos[p], b = pos[Pq + p];
    float acc = 0.f;
    for (int k0 = 0; k0 < Nn; k0 += 64) {
        int m1 = M[a * Nn + k0 + lane];
        int m2 = MT[b * Nn + k0 + lane];
        unsigned long long mask = __ballot(m1 >= 0 && m2 >= 0);
        while (mask) {
            int i = __ffsll(mask) - 1;
            mask &= mask - 1;
            int e1 = __shfl(m1, i);
            int e2 = __shfl(m2, i);
            acc += x2buf[e1 * 64 + lane] * x1buf[e2 * 64 + lane];
        }
    }
    feat[p * 128 + lane] = acc;
}

// ---------------- final MLP: relu(feat@Wa+ba) @ Wb + bb ----------------
__global__ __launch_bounds__(256) void k_final(const float* __restrict__ feat,
                                               const float* __restrict__ Wa,
                                               const float* __restrict__ ba,
                                               const float* __restrict__ Wb,
                                               const float* __restrict__ bb,
                                               float* __restrict__ out) {
    int tid = threadIdx.x;
    int lane = tid & 63;
    int p = blockIdx.x * 4 + (tid >> 6);
    float f0 = feat[p * 128 + lane];
    float f1 = feat[p * 128 + 64 + lane];
    float acc = ba[lane];
    #pragma unroll 8
    for (int j = 0; j < 64; ++j) {
        acc += __shfl(f0, j) * Wa[j * 64 + lane];
        acc += __shfl(f1, j) * Wa[(64 + j) * 64 + lane];
    }
    acc = fmaxf(acc, 0.f);
    float v = acc * Wb[lane];
    for (int off = 32; off; off >>= 1) v += __shfl_xor(v, off);
    if (lane == 0) out[p] = v + bb[0];
}

extern "C" void kernel_launch(void* const* d_in, const int* in_sizes, int n_in,
                              void* d_out, int out_size, void* d_ws, size_t ws_size,
                              hipStream_t stream) {
    const float* x    = (const float*)d_in[0];
    const int*   ei   = (const int*)d_in[1];
    const int*   pos  = (const int*)d_in[2];
    const float* Wg1  = (const float*)d_in[3];
    const float* bg1  = (const float*)d_in[4];
    const float* Wg2  = (const float*)d_in[5];
    const float* bg2  = (const float*)d_in[6];
    const float* Wm1  = (const float*)d_in[7];
    const float* bm1  = (const float*)d_in[8];
    const float* gm1  = (const float*)d_in[9];
    const float* bem1 = (const float*)d_in[10];
    const float* Wm2  = (const float*)d_in[11];
    const float* bm2  = (const float*)d_in[12];
    const float* gm2  = (const float*)d_in[13];
    const float* bem2 = (const float*)d_in[14];
    const float* Wa   = (const float*)d_in[15];
    const float* ba   = (const float*)d_in[16];
    const float* Wb   = (const float*)d_in[17];
    const float* bb   = (const float*)d_in[18];
    float* out = (float*)d_out;

    char* w = (char*)d_ws;
    float* deg   = (float*)w;  w += 1024 * 4;
    float* dinv  = (float*)w;  w += 1024 * 4;
    float* xw    = (float*)w;  w += 65536 * 4;
    float* h1    = (float*)w;  w += 65536 * 4;
    float* h2    = (float*)w;  w += 65536 * 4;
    float* feat  = (float*)w;  w += (size_t)Pq * 128 * 4;
    float* x1buf = (float*)w;  w += (size_t)Ee * 64 * 4;
    float* x2buf = (float*)w;  w += (size_t)Ee * 64 * 4;
    int*   M     = (int*)w;    w += (size_t)Nn * Nn * 4;
    int*   MT    = (int*)w;    w += (size_t)Nn * Nn * 4;

    hipMemsetAsync(deg, 0, 1024 * 4, stream);
    hipMemsetAsync(h1, 0, 65536 * 4, stream);
    hipMemsetAsync(h2, 0, 65536 * 4, stream);
    hipMemsetAsync(M, 0xFF, (size_t)Nn * Nn * 4 * 2, stream);  // M and MT contiguous

    k_deg<<<Ee / 256, 256, 0, stream>>>(ei, deg);
    k_dinv<<<Nn / 256, 256, 0, stream>>>(deg, dinv);

    // GCN layer 1
    k_xw<Din><<<Nn * 64 / 256, 256, 0, stream>>>(x, Wg1, xw);
    k_scatter<<<(size_t)Ee * 64 / 256, 256, 0, stream>>>(ei, xw, dinv, h1);
    k_selfloop<<<Nn * 64 / 256, 256, 0, stream>>>(h1, xw, dinv, bg1);

    // GCN layer 2
    k_xw<Hh><<<Nn * 64 / 256, 256, 0, stream>>>(h1, Wg2, xw);
    k_scatter<<<(size_t)Ee * 64 / 256, 256, 0, stream>>>(ei, xw, dinv, h2);
    k_selfloop<<<Nn * 64 / 256, 256, 0, stream>>>(h2, xw, dinv, bg2);

    // edge maps + edge MLP heads
    k_buildM<<<Ee / 256, 256, 0, stream>>>(ei, M, MT);
    k_mlp_edges<<<512, 256, 0, stream>>>(ei, h2, Wm1, bm1, gm1, bem1,
                                         Wm2, bm2, gm2, bem2, x1buf, x2buf);

    // features + bilinear sparse product
    k_xx<<<Pq * 64 / 256, 256, 0, stream>>>(pos, h2, feat);
    k_posval<<<Pq, 64, 0, stream>>>(pos, M, MT, x1buf, x2buf, feat);

    // final MLP
    k_final<<<Pq / 4, 256, 0, stream>>>(feat, Wa, ba, Wb, bb, out);
}

// Round 2
// 177.408 us; speedup vs baseline: 1.1905x; 1.1905x over previous
//
#include <hip/hip_runtime.h>

#define Nn 1024
#define Ee 65536
#define Pq 1024
#define Din 128
#define Hh 64

// ---------------- degree / norm ----------------
__global__ void k_deg(const int* __restrict__ ei, float* __restrict__ deg) {
    int e = blockIdx.x * blockDim.x + threadIdx.x;
    if (e < Ee) atomicAdd(&deg[ei[Ee + e]], 1.0f);
}

__global__ void k_dinv(const float* __restrict__ deg, float* __restrict__ dinv) {
    int i = blockIdx.x * blockDim.x + threadIdx.x;
    if (i < Nn) dinv[i] = rsqrtf(deg[i] + 1.0f);
}

// ---------------- xw = X @ W  (X:[Nn,K], W:[K,64]) ----------------
template <int K>
__global__ void k_xw(const float* __restrict__ X, const float* __restrict__ W,
                     float* __restrict__ xw) {
    int gid = blockIdx.x * blockDim.x + threadIdx.x;  // Nn*64 threads
    int r = gid >> 6, c = gid & 63;
    float acc = 0.f;
    #pragma unroll 8
    for (int j = 0; j < K; ++j) acc += X[r * K + j] * W[j * 64 + c];
    xw[gid] = acc;
}

// ---------------- GCN scatter: out[col] += xw[row]*dinv[row]*dinv[col] ----------------
__global__ void k_scatter(const int* __restrict__ ei, const float* __restrict__ xw,
                          const float* __restrict__ dinv, float* __restrict__ out) {
    int gid = blockIdx.x * blockDim.x + threadIdx.x;  // Ee*64 threads
    int e = gid >> 6, c = gid & 63;
    int r = ei[e], cl = ei[Ee + e];
    atomicAdd(&out[cl * 64 + c], xw[r * 64 + c] * dinv[r] * dinv[cl]);
}

// ---------------- self-loop message + bias ----------------
__global__ void k_selfloop(float* __restrict__ out, const float* __restrict__ xw,
                           const float* __restrict__ dinv, const float* __restrict__ b) {
    int gid = blockIdx.x * blockDim.x + threadIdx.x;  // Nn*64
    int n = gid >> 6, c = gid & 63;
    float di = dinv[n];
    out[gid] += xw[gid] * di * di + b[c];
}

// ---------------- edge-index maps (last-edge-wins == max id; dup edges have equal values) ----------------
__global__ void k_buildM(const int* __restrict__ ei, int* __restrict__ M, int* __restrict__ MT) {
    int e = blockIdx.x * blockDim.x + threadIdx.x;
    if (e < Ee) {
        int r = ei[e], cl = ei[Ee + e];
        atomicMax(&M[r * Nn + cl], e);
        atomicMax(&MT[cl * Nn + r], e);
    }
}

// ---------------- per-edge MLP heads, lane = edge ----------------
// Each lane owns one edge: xe[64] in regs, W read via uniform (scalar) loads,
// matmul is a pure v_fma_f32 stream, LN is lane-local. No LDS, no shfl.
__global__ __launch_bounds__(256, 1) void k_mlp_edges2(
    const int* __restrict__ ei, const float* __restrict__ h2,
    const float* __restrict__ W1, const float* __restrict__ b1,
    const float* __restrict__ g1, const float* __restrict__ be1,
    const float* __restrict__ W2, const float* __restrict__ b2,
    const float* __restrict__ g2, const float* __restrict__ be2,
    float* __restrict__ x1buf, float* __restrict__ x2buf) {
    int tid = threadIdx.x;
    int lane = tid & 63;
    int e = (blockIdx.x * 4 + (tid >> 6)) * 64 + lane;
    int r = ei[e], cl = ei[Ee + e];

    const float4* hr = (const float4*)(h2 + r * 64);
    const float4* hc = (const float4*)(h2 + cl * 64);
    float4 va[16], vb[16];
    #pragma unroll
    for (int k = 0; k < 16; ++k) va[k] = hr[k];
    #pragma unroll
    for (int k = 0; k < 16; ++k) vb[k] = hc[k];
    float xe[64];
    #pragma unroll
    for (int k = 0; k < 16; ++k) {
        xe[4 * k + 0] = va[k].x * vb[k].x;
        xe[4 * k + 1] = va[k].y * vb[k].y;
        xe[4 * k + 2] = va[k].z * vb[k].z;
        xe[4 * k + 3] = va[k].w * vb[k].w;
    }

    float acc[64];

    // ---- head 1 ----
    #pragma unroll
    for (int c = 0; c < 64; ++c) acc[c] = b1[c];
    #pragma unroll 4
    for (int j = 0; j < 64; ++j) {
        float xj = xe[j];
        #pragma unroll
        for (int c = 0; c < 64; ++c) acc[c] = fmaf(xj, W1[j * 64 + c], acc[c]);
    }
    {
        float s0 = 0, s1 = 0, s2 = 0, s3 = 0, q0 = 0, q1 = 0, q2 = 0, q3 = 0;
        #pragma unroll
        for (int c = 0; c < 64; c += 4) {
            s0 += acc[c];     q0 += acc[c] * acc[c];
            s1 += acc[c + 1]; q1 += acc[c + 1] * acc[c + 1];
            s2 += acc[c + 2]; q2 += acc[c + 2] * acc[c + 2];
            s3 += acc[c + 3]; q3 += acc[c + 3] * acc[c + 3];
        }
        float s = (s0 + s1) + (s2 + s3);
        float q = (q0 + q1) + (q2 + q3);
        float mu = s * (1.f / 64.f);
        float var = q * (1.f / 64.f) - mu * mu;
        float rinv = rsqrtf(var + 1e-5f);
        float4* o = (float4*)(x1buf + (size_t)e * 64);
        #pragma unroll
        for (int k = 0; k < 16; ++k) {
            float4 ov;
            ov.x = fmaxf(0.f, (acc[4 * k + 0] - mu) * rinv * g1[4 * k + 0] + be1[4 * k + 0]);
            ov.y = fmaxf(0.f, (acc[4 * k + 1] - mu) * rinv * g1[4 * k + 1] + be1[4 * k + 1]);
            ov.z = fmaxf(0.f, (acc[4 * k + 2] - mu) * rinv * g1[4 * k + 2] + be1[4 * k + 2]);
            ov.w = fmaxf(0.f, (acc[4 * k + 3] - mu) * rinv * g1[4 * k + 3] + be1[4 * k + 3]);
            o[k] = ov;
        }
    }

    // ---- head 2 ----
    #pragma unroll
    for (int c = 0; c < 64; ++c) acc[c] = b2[c];
    #pragma unroll 4
    for (int j = 0; j < 64; ++j) {
        float xj = xe[j];
        #pragma unroll
        for (int c = 0; c < 64; ++c) acc[c] = fmaf(xj, W2[j * 64 + c], acc[c]);
    }
    {
        float s0 = 0, s1 = 0, s2 = 0, s3 = 0, q0 = 0, q1 = 0, q2 = 0, q3 = 0;
        #pragma unroll
        for (int c = 0; c < 64; c += 4) {
            s0 += acc[c];     q0 += acc[c] * acc[c];
            s1 += acc[c + 1]; q1 += acc[c + 1] * acc[c + 1];
            s2 += acc[c + 2]; q2 += acc[c + 2] * acc[c + 2];
            s3 += acc[c + 3]; q3 += acc[c + 3] * acc[c + 3];
        }
        float s = (s0 + s1) + (s2 + s3);
        float q = (q0 + q1) + (q2 + q3);
        float mu = s * (1.f / 64.f);
        float var = q * (1.f / 64.f) - mu * mu;
        float rinv = rsqrtf(var + 1e-5f);
        float4* o = (float4*)(x2buf + (size_t)e * 64);
        #pragma unroll
        for (int k = 0; k < 16; ++k) {
            float4 ov;
            ov.x = fmaxf(0.f, (acc[4 * k + 0] - mu) * rinv * g2[4 * k + 0] + be2[4 * k + 0]);
            ov.y = fmaxf(0.f, (acc[4 * k + 1] - mu) * rinv * g2[4 * k + 1] + be2[4 * k + 1]);
            ov.z = fmaxf(0.f, (acc[4 * k + 2] - mu) * rinv * g2[4 * k + 2] + be2[4 * k + 2]);
            ov.w = fmaxf(0.f, (acc[4 * k + 3] - mu) * rinv * g2[4 * k + 3] + be2[4 * k + 3]);
            o[k] = ov;
        }
    }
}

// ---------------- xx pairs -> feat[:,64:128] ----------------
__global__ void k_xx(const int* __restrict__ pos, const float* __restrict__ h2,
                     float* __restrict__ feat) {
    int gid = blockIdx.x * blockDim.x + threadIdx.x;  // Pq*64
    int p = gid >> 6, c = gid & 63;
    feat[p * 128 + 64 + c] = h2[pos[p] * 64 + c] * h2[pos[Pq + p] * 64 + c];
}

// ---------------- pos_val[p,h] = sum_k x2[M[a,k]] * x1[MT[b,k]] -> feat[:,0:64] ----------------
__global__ __launch_bounds__(64) void k_posval(const int* __restrict__ pos,
                                               const int* __restrict__ M,
                                               const int* __restrict__ MT,
                                               const float* __restrict__ x1buf,
                                               const float* __restrict__ x2buf,
                                               float* __restrict__ feat) {
    int p = blockIdx.x;
    int lane = threadIdx.x;
    int a = pos[p], b = pos[Pq + p];
    float acc = 0.f;
    for (int k0 = 0; k0 < Nn; k0 += 64) {
        int m1 = M[a * Nn + k0 + lane];
        int m2 = MT[b * Nn + k0 + lane];
        unsigned long long mask = __ballot(m1 >= 0 && m2 >= 0);
        while (mask) {
            int i = __ffsll(mask) - 1;
            mask &= mask - 1;
            int e1 = __shfl(m1, i);
            int e2 = __shfl(m2, i);
            acc += x2buf[e1 * 64 + lane] * x1buf[e2 * 64 + lane];
        }
    }
    feat[p * 128 + lane] = acc;
}

// ---------------- final MLP: relu(feat@Wa+ba) @ Wb + bb ----------------
__global__ __launch_bounds__(256) void k_final(const float* __restrict__ feat,
                                               const float* __restrict__ Wa,
                                               const float* __restrict__ ba,
                                               const float* __restrict__ Wb,
                                               const float* __restrict__ bb,
                                               float* __restrict__ out) {
    int tid = threadIdx.x;
    int lane = tid & 63;
    int p = blockIdx.x * 4 + (tid >> 6);
    float f0 = feat[p * 128 + lane];
    float f1 = feat[p * 128 + 64 + lane];
    float acc = ba[lane];
    #pragma unroll 8
    for (int j = 0; j < 64; ++j) {
        acc += __shfl(f0, j) * Wa[j * 64 + lane];
        acc += __shfl(f1, j) * Wa[(64 + j) * 64 + lane];
    }
    acc = fmaxf(acc, 0.f);
    float v = acc * Wb[lane];
    for (int off = 32; off; off >>= 1) v += __shfl_xor(v, off);
    if (lane == 0) out[p] = v + bb[0];
}

extern "C" void kernel_launch(void* const* d_in, const int* in_sizes, int n_in,
                              void* d_out, int out_size, void* d_ws, size_t ws_size,
                              hipStream_t stream) {
    const float* x    = (const float*)d_in[0];
    const int*   ei   = (const int*)d_in[1];
    const int*   pos  = (const int*)d_in[2];
    const float* Wg1  = (const float*)d_in[3];
    const float* bg1  = (const float*)d_in[4];
    const float* Wg2  = (const float*)d_in[5];
    const float* bg2  = (const float*)d_in[6];
    const float* Wm1  = (const float*)d_in[7];
    const float* bm1  = (const float*)d_in[8];
    const float* gm1  = (const float*)d_in[9];
    const float* bem1 = (const float*)d_in[10];
    const float* Wm2  = (const float*)d_in[11];
    const float* bm2  = (const float*)d_in[12];
    const float* gm2  = (const float*)d_in[13];
    const float* bem2 = (const float*)d_in[14];
    const float* Wa   = (const float*)d_in[15];
    const float* ba   = (const float*)d_in[16];
    const float* Wb   = (const float*)d_in[17];
    const float* bb   = (const float*)d_in[18];
    float* out = (float*)d_out;

    char* w = (char*)d_ws;
    float* deg   = (float*)w;  w += 1024 * 4;
    float* dinv  = (float*)w;  w += 1024 * 4;
    float* xw    = (float*)w;  w += 65536 * 4;
    float* h1    = (float*)w;  w += 65536 * 4;
    float* h2    = (float*)w;  w += 65536 * 4;
    float* feat  = (float*)w;  w += (size_t)Pq * 128 * 4;
    float* x1buf = (float*)w;  w += (size_t)Ee * 64 * 4;
    float* x2buf = (float*)w;  w += (size_t)Ee * 64 * 4;
    int*   M     = (int*)w;    w += (size_t)Nn * Nn * 4;
    int*   MT    = (int*)w;    w += (size_t)Nn * Nn * 4;

    hipMemsetAsync(deg, 0, 1024 * 4, stream);
    hipMemsetAsync(h1, 0, 65536 * 4, stream);
    hipMemsetAsync(h2, 0, 65536 * 4, stream);
    hipMemsetAsync(M, 0xFF, (size_t)Nn * Nn * 4 * 2, stream);  // M and MT contiguous

    k_deg<<<Ee / 256, 256, 0, stream>>>(ei, deg);
    k_dinv<<<Nn / 256, 256, 0, stream>>>(deg, dinv);

    // GCN layer 1
    k_xw<Din><<<Nn * 64 / 256, 256, 0, stream>>>(x, Wg1, xw);
    k_scatter<<<(size_t)Ee * 64 / 256, 256, 0, stream>>>(ei, xw, dinv, h1);
    k_selfloop<<<Nn * 64 / 256, 256, 0, stream>>>(h1, xw, dinv, bg1);

    // GCN layer 2
    k_xw<Hh><<<Nn * 64 / 256, 256, 0, stream>>>(h1, Wg2, xw);
    k_scatter<<<(size_t)Ee * 64 / 256, 256, 0, stream>>>(ei, xw, dinv, h2);
    k_selfloop<<<Nn * 64 / 256, 256, 0, stream>>>(h2, xw, dinv, bg2);

    // edge maps + edge MLP heads
    k_buildM<<<Ee / 256, 256, 0, stream>>>(ei, M, MT);
    k_mlp_edges2<<<Ee / 256, 256, 0, stream>>>(ei, h2, Wm1, bm1, gm1, bem1,
                                               Wm2, bm2, gm2, bem2, x1buf, x2buf);

    // features + bilinear sparse product
    k_xx<<<Pq * 64 / 256, 256, 0, stream>>>(pos, h2, feat);
    k_posval<<<Pq, 64, 0, stream>>>(pos, M, MT, x1buf, x2buf, feat);

    // final MLP
    k_final<<<Pq / 4, 256, 0, stream>>>(feat, Wa, ba, Wb, bb, out);
}